// Round 2
// baseline (183.483 us; speedup 1.0000x reference)
//
#include <hip/hip_runtime.h>
#include <math.h>

// Problem constants (fixed by setup_inputs)
constexpr int B_ = 8;
constexpr int N_ = 16384;
constexpr int M_ = 1024;
constexpr int C_ = 256;
constexpr int NCHUNK = 8;
constexpr int CHUNK = M_ / NCHUNK;  // 128
constexpr int KEEP = 4;             // per-chunk survivors
constexpr int TOPK_BLOCK = 1024;
constexpr int TKB_PER_B = (N_ / TOPK_BLOCK) * NCHUNK;  // 128 topk blocks per batch
constexpr int MG_PTS = 256;                            // points per mg block
constexpr int MGB_PER_B = N_ / MG_PTS;                 // 64 mg blocks per batch

// 4-deep sorted-insert network on POSITIVE floats (P0<=P1<=P2<=P3 invariant).
#define INSERT4(P, u)                                              \
  {                                                                \
    const float o0 = P##0, o1 = P##1, o2 = P##2;                   \
    P##0 = fminf(o0, (u));                                         \
    P##1 = __builtin_amdgcn_fmed3f(o0, P##1, (u));                 \
    P##2 = __builtin_amdgcn_fmed3f(o1, P##2, (u));                 \
    P##3 = __builtin_amdgcn_fmed3f(o2, P##3, (u));                 \
  }

// ---------------------------------------------------------------------------
// Kernel 0 (fused prep): blocks [0,32) pack centroids; blocks [32, 32+2048)
// transpose centroid_f [B,C,M] -> fT [B,M,C] via 32x32 LDS tiles (+1 pad).
// ---------------------------------------------------------------------------
__global__ __launch_bounds__(256) void prep_kernel(
    const float* __restrict__ cxyz,  // [B, M, 3]
    const float* __restrict__ cf,    // [B, C, M]
    float* __restrict__ csoa,        // [B][NCHUNK][CHUNK/2][8]
    float4* __restrict__ cpack,      // [B*M]
    float* __restrict__ fT)          // [B, M, C]
{
  __shared__ float tile[32][33];
  const int tx = threadIdx.x;  // 0..31
  const int ty = threadIdx.y;  // 0..7
  if (blockIdx.x < 32) {
    // ---- pack role ----
    const int i = blockIdx.x * 256 + (ty * 32 + tx);  // global centroid id
    if (i < B_ * M_) {
      const int b = i >> 10;         // / M_
      const int m = i & (M_ - 1);
      const int chunk = m >> 7;      // / CHUNK
      const int mi = m & (CHUNK - 1);
      const int pair = mi >> 1;
      const int sub = mi & 1;
      const float x = cxyz[3 * i + 0];
      const float y = cxyz[3 * i + 1];
      const float z = cxyz[3 * i + 2];
      const float w = x * x + y * y + z * z;
      float* pb = csoa + ((((size_t)b * NCHUNK + chunk) * (CHUNK / 2)) + pair) * 8 + sub;
      pb[0] = x; pb[2] = y; pb[4] = z; pb[6] = w;
      cpack[i] = make_float4(x, y, z, w);
    }
  } else {
    // ---- transpose role ----
    const int bid = blockIdx.x - 32;       // 0..2047
    const int m0 = (bid & 31) * 32;        // M/32 = 32
    const int c0 = ((bid >> 5) & 7) * 32;  // C/32 = 8
    const int b = bid >> 8;
    const float* fb = cf + (size_t)b * C_ * M_;
    float* ftb = fT + (size_t)b * M_ * C_;
#pragma unroll
    for (int j = 0; j < 32; j += 8)
      tile[ty + j][tx] = fb[(size_t)(c0 + ty + j) * M_ + (m0 + tx)];
    __syncthreads();
#pragma unroll
    for (int j = 0; j < 32; j += 8)
      ftb[(size_t)(m0 + ty + j) * C_ + (c0 + tx)] = tile[tx][ty + j];
  }
}

// ---------------------------------------------------------------------------
// Pipelined step kernel. One launch = one pipeline stage:
//   topk role  (VALU-bound, ~zero HBM): batches [tk_b0, tk_b0+tk_nb)
//   mg role    (HBM-write-bound, ~zero VALU): merge+gather for batches
//              [mg_b0, mg_b0+mg_nb), reading cand written by the PREVIOUS
//              launch (stream order provides sync + cross-XCD visibility).
// Roles striped every 3rd block (T:G = 2:1): with one 16-wave block per CU,
// at any instant ~2/3 of CUs run VALU-bound topk while ~1/3 drive the HBM
// write port -- chip-level pipe overlap.
// __launch_bounds__(1024, 4): VGPR cap 128 (merge's f64 path needs ~90).
// R1's (1024,8) capped at 64 VGPR -> spilled BOTH roles -> 167us. Fixed.
// All inner math byte-identical to the proven 4-kernel version.
// ---------------------------------------------------------------------------
__global__ __launch_bounds__(1024, 4) void step_kernel(
    const float* __restrict__ xyz,     // [B, N, 3]
    const float* __restrict__ csoa,    // [B][NCHUNK][CHUNK/2][8]
    const float4* __restrict__ cpack,  // [B*M]
    const float* __restrict__ fT,      // [B, M, C]
    unsigned* __restrict__ cand,       // [B*N][NCHUNK]
    float* __restrict__ out,           // [B, N, C]
    int tk_b0, int tk_nb, int mg_b0, int mg_nb)
{
  const int T = tk_nb * TKB_PER_B;   // topk blocks this launch
  const int G = mg_nb * MGB_PER_B;   // mg blocks this launch
  const int bid = blockIdx.x;
  bool is_mg; int rid;
  if (G == 0)      { is_mg = false; rid = bid; }
  else if (T == 0) { is_mg = true;  rid = bid; }
  else {  // schedule guarantees T == 2*G: stripe every 3rd block as mg
    is_mg = ((bid % 3) == 2);
    rid = is_mg ? (bid / 3) : (bid - (bid + 1) / 3);
  }

  if (!is_mg) {
    // ================= topk role (verbatim R8 structure) =================
    const int b = tk_b0 + (rid >> 7);        // rid / 128
    const int r = rid & 127;
    const int chunk = r >> 4;                // 8 chunks
    const int n = (r & 15) * TOPK_BLOCK + threadIdx.x;
    const size_t p = (size_t)b * N_ + n;

    const float* __restrict__ cb =
        csoa + (((size_t)b * NCHUNK + chunk) * (CHUNK / 2)) * 8;

    const float* xp = xyz + p * 3;
    const float x0 = xp[0], x1 = xp[1], x2 = xp[2];
    const float nx0 = -2.f * x0, nx1 = -2.f * x1, nx2 = -2.f * x2;
    const float x2p1 = fmaf(x0, x0, fmaf(x1, x1, fmaf(x2, x2, 1.0f)));

    float A0 = INFINITY, A1 = INFINITY, A2 = INFINITY, A3 = INFINITY;
    float B0 = INFINITY, B1 = INFINITY, B2 = INFINITY, B3 = INFINITY;

#pragma unroll 8
    for (int i = 0; i < CHUNK / 2; ++i) {
      const float* pb = cb + i * 8;
      float tx = fmaf(nx0, pb[0], x2p1), ty = fmaf(nx0, pb[1], x2p1);
      tx = fmaf(nx1, pb[2], tx); ty = fmaf(nx1, pb[3], ty);
      tx = fmaf(nx2, pb[4], tx); ty = fmaf(nx2, pb[5], ty);
      tx += pb[6]; ty += pb[7];  // key = d^2 + 1 > 0
      const float kx = __uint_as_float((__float_as_uint(tx) & 0xFFFFFF80u) | (unsigned)(2 * i));
      const float ky = __uint_as_float((__float_as_uint(ty) & 0xFFFFFF80u) | (unsigned)(2 * i + 1));
      INSERT4(A, kx);
      INSERT4(B, ky);
    }
    INSERT4(A, B0);
    INSERT4(A, B1);
    INSERT4(A, B2);
    INSERT4(A, B3);

    const unsigned i0 = __float_as_uint(A0) & 127u;
    const unsigned i1 = __float_as_uint(A1) & 127u;
    const unsigned i2 = __float_as_uint(A2) & 127u;
    const unsigned i3 = __float_as_uint(A3) & 127u;
    cand[p * NCHUNK + chunk] = i0 | (i1 << 8) | (i2 << 16) | (i3 << 24);
  } else {
    // ============= mg role: merge (phase A) + gather (phase B) ===========
    __shared__ int   sI[MG_PTS * 3];
    __shared__ float sW[MG_PTS * 3];
    const int b = mg_b0 + (rid >> 6);        // rid / 64
    const size_t pbase = (size_t)b * N_ + (size_t)(rid & 63) * MG_PTS;
    const int tid = threadIdx.x;

    if (tid < MG_PTS) {
      // ---- merge body (verbatim: f64 re-rank, stable strict-< insert) ----
      const size_t p = pbase + tid;
      const float* xp = xyz + p * 3;
      const double x0d = (double)xp[0], x1d = (double)xp[1], x2d = (double)xp[2];
      const float4* __restrict__ cb = cpack + (size_t)b * M_;

      const uint4* cw4 = (const uint4*)(cand + p * NCHUNK);
      const uint4 ca = cw4[0], cb2 = cw4[1];
      unsigned words[NCHUNK] = {ca.x, ca.y, ca.z, ca.w, cb2.x, cb2.y, cb2.z, cb2.w};

      double D0 = 1e300, D1 = 1e300, D2 = 1e300;
      int I0 = 0, I1 = 0, I2 = 0;
#pragma unroll
      for (int ch = 0; ch < NCHUNK; ++ch) {
        const unsigned w = words[ch];
#pragma unroll
        for (int j = 0; j < KEEP; ++j) {
          const int m = ch * CHUNK + (int)((w >> (8 * j)) & 255u);
          const float4 c = cb[m];
          const double cx = (double)c.x, cy = (double)c.y, cz = (double)c.z;
          const double dot = x0d * cx + x1d * cy + x2d * cz;
          const double c2d = cx * cx + cy * cy + cz * cz;
          const double kd = c2d - 2.0 * dot;
          if (kd < D2) {
            if (kd < D1) {
              D2 = D1; I2 = I1;
              if (kd < D0) { D1 = D0; I1 = I0; D0 = kd; I0 = m; }
              else         { D1 = kd; I1 = m; }
            } else {
              D2 = kd; I2 = m;
            }
          }
        }
      }

      const double xx = x0d * x0d + x1d * x1d + x2d * x2d;
      const float d0 = sqrtf(fmaxf((float)(xx + D0), 0.0f));
      const float d1 = sqrtf(fmaxf((float)(xx + D1), 0.0f));
      const float d2 = sqrtf(fmaxf((float)(xx + D2), 0.0f));
      float w0 = 1.0f / fmaxf(d0, 1e-8f);
      float w1 = 1.0f / fmaxf(d1, 1e-8f);
      float w2 = 1.0f / fmaxf(d2, 1e-8f);
      const float wsum = w0 + w1 + w2;
      w0 /= wsum; w1 /= wsum; w2 /= wsum;

      sI[tid * 3 + 0] = I0; sI[tid * 3 + 1] = I1; sI[tid * 3 + 2] = I2;
      sW[tid * 3 + 0] = w0; sW[tid * 3 + 1] = w1; sW[tid * 3 + 2] = w2;
    }
    __syncthreads();

    // ---- gather body (verbatim pattern): wave-per-point, lane=4 channels ----
    const int wid = tid >> 6;
    const int lane = tid & 63;
    const float4* __restrict__ f4 = (const float4*)(fT + (size_t)b * M_ * C_);
#pragma unroll 4
    for (int j = 0; j < MG_PTS / 16; ++j) {   // 16 waves x 16 points
      const int li = wid * 16 + j;
      const size_t p = pbase + li;
      const int i0 = sI[li * 3 + 0], i1 = sI[li * 3 + 1], i2 = sI[li * 3 + 2];
      const float w0 = sW[li * 3 + 0], w1 = sW[li * 3 + 1], w2 = sW[li * 3 + 2];

      float4 a  = f4[(size_t)i0 * (C_ / 4) + lane];
      float4 bb = f4[(size_t)i1 * (C_ / 4) + lane];
      float4 c  = f4[(size_t)i2 * (C_ / 4) + lane];

      float4 rr;
      rr.x = w0 * a.x + w1 * bb.x + w2 * c.x;
      rr.y = w0 * a.y + w1 * bb.y + w2 * c.y;
      rr.z = w0 * a.z + w1 * bb.z + w2 * c.z;
      rr.w = w0 * a.w + w1 * bb.w + w2 * c.w;

      ((float4*)out)[p * (C_ / 4) + lane] = rr;
    }
  }
}

extern "C" void kernel_launch(void* const* d_in, const int* in_sizes, int n_in,
                              void* d_out, int out_size, void* d_ws, size_t ws_size,
                              hipStream_t stream) {
  const float* xyz  = (const float*)d_in[0];  // [B, N, 3]
  const float* cxyz = (const float*)d_in[1];  // [B, M, 3]
  const float* cf   = (const float*)d_in[2];  // [B, C, M]
  float* out = (float*)d_out;                 // [B, N, C]

  char* ws = (char*)d_ws;
  float4* cpack = (float4*)ws;                          // B*M float4 (128 KB)
  size_t off = (size_t)B_ * M_ * sizeof(float4);
  float* csoa = (float*)(ws + off);                     // B*M*4 floats (128 KB)
  off += (size_t)B_ * M_ * 4 * sizeof(float);
  off = (off + 255) & ~(size_t)255;
  unsigned* cand = (unsigned*)(ws + off);               // B*N*NCHUNK*4B = 4.2 MB
  off += ((size_t)B_ * N_ * NCHUNK * 4 + 255) & ~(size_t)255;
  float* fT = (float*)(ws + off);                       // B*M*C floats = 8 MB

  // Pipeline (2 batches per stage, stream order = stage barrier):
  //   L0 prep | L1 tk(0,1) | L2 tk(2,3)||mg(0,1) | L3 tk(4,5)||mg(2,3)
  //   L4 tk(6,7)||mg(4,5) | L5 mg(6,7)
  prep_kernel<<<dim3(32 + 2048), dim3(32, 8), 0, stream>>>(
      cxyz, cf, csoa, cpack, fT);
  step_kernel<<<dim3(2 * TKB_PER_B), 1024, 0, stream>>>(
      xyz, csoa, cpack, fT, cand, out, 0, 2, 0, 0);
  step_kernel<<<dim3(2 * TKB_PER_B + 2 * MGB_PER_B), 1024, 0, stream>>>(
      xyz, csoa, cpack, fT, cand, out, 2, 2, 0, 2);
  step_kernel<<<dim3(2 * TKB_PER_B + 2 * MGB_PER_B), 1024, 0, stream>>>(
      xyz, csoa, cpack, fT, cand, out, 4, 2, 2, 2);
  step_kernel<<<dim3(2 * TKB_PER_B + 2 * MGB_PER_B), 1024, 0, stream>>>(
      xyz, csoa, cpack, fT, cand, out, 6, 2, 4, 2);
  step_kernel<<<dim3(2 * MGB_PER_B), 1024, 0, stream>>>(
      xyz, csoa, cpack, fT, cand, out, 0, 0, 6, 2);
}

// Round 4
// 108.042 us; speedup vs baseline: 1.6983x; 1.6983x over previous
//
#include <hip/hip_runtime.h>
#include <math.h>

// Problem constants (fixed by setup_inputs)
constexpr int B_ = 8;
constexpr int N_ = 16384;
constexpr int M_ = 1024;
constexpr int C_ = 256;
constexpr int NCHUNK = 8;
constexpr int CHUNK = M_ / NCHUNK;  // 128
constexpr int KEEP = 4;             // per-chunk survivors
constexpr int TOPK_BLOCK = 1024;    // 16 waves/block -> 2 blocks/CU -> 2 K$ streams

// native 4-float vector for __builtin_nontemporal_store (HIP's float4 is a
// class type the builtin rejects; ext_vector_type is accepted).
typedef float nfloat4 __attribute__((ext_vector_type(4)));

// 4-deep sorted-insert network on POSITIVE floats (P0<=P1<=P2<=P3 invariant).
// min + 3x v_med3_f32, all VOP3-legal, no SGPR operands.
#define INSERT4(P, u)                                              \
  {                                                                \
    const float o0 = P##0, o1 = P##1, o2 = P##2;                   \
    P##0 = fminf(o0, (u));                                         \
    P##1 = __builtin_amdgcn_fmed3f(o0, P##1, (u));                 \
    P##2 = __builtin_amdgcn_fmed3f(o1, P##2, (u));                 \
    P##3 = __builtin_amdgcn_fmed3f(o2, P##3, (u));                 \
  }

// ---------------------------------------------------------------------------
// Kernel 0 (fused prep): blocks [0,32) pack centroids; blocks [32, 32+2048)
// transpose centroid_f [B,C,M] -> fT [B,M,C] via 32x32 LDS tiles (+1 pad).
// ---------------------------------------------------------------------------
__global__ __launch_bounds__(256) void prep_kernel(
    const float* __restrict__ cxyz,  // [B, M, 3]
    const float* __restrict__ cf,    // [B, C, M]
    float* __restrict__ csoa,        // [B][NCHUNK][CHUNK/2][8]
    float4* __restrict__ cpack,      // [B*M]
    float* __restrict__ fT)          // [B, M, C]
{
  __shared__ float tile[32][33];
  const int tx = threadIdx.x;  // 0..31
  const int ty = threadIdx.y;  // 0..7
  if (blockIdx.x < 32) {
    // ---- pack role ----
    const int i = blockIdx.x * 256 + (ty * 32 + tx);  // global centroid id
    if (i < B_ * M_) {
      const int b = i >> 10;         // / M_
      const int m = i & (M_ - 1);
      const int chunk = m >> 7;      // / CHUNK
      const int mi = m & (CHUNK - 1);
      const int pair = mi >> 1;
      const int sub = mi & 1;
      const float x = cxyz[3 * i + 0];
      const float y = cxyz[3 * i + 1];
      const float z = cxyz[3 * i + 2];
      const float w = x * x + y * y + z * z;
      float* pb = csoa + ((((size_t)b * NCHUNK + chunk) * (CHUNK / 2)) + pair) * 8 + sub;
      pb[0] = x; pb[2] = y; pb[4] = z; pb[6] = w;
      cpack[i] = make_float4(x, y, z, w);
    }
  } else {
    // ---- transpose role ----
    const int bid = blockIdx.x - 32;       // 0..2047
    const int m0 = (bid & 31) * 32;        // M/32 = 32
    const int c0 = ((bid >> 5) & 7) * 32;  // C/32 = 8
    const int b = bid >> 8;
    const float* fb = cf + (size_t)b * C_ * M_;
    float* ftb = fT + (size_t)b * M_ * C_;
#pragma unroll
    for (int j = 0; j < 32; j += 8)
      tile[ty + j][tx] = fb[(size_t)(c0 + ty + j) * M_ + (m0 + tx)];
    __syncthreads();
#pragma unroll
    for (int j = 0; j < 32; j += 8)
      ftb[(size_t)(m0 + ty + j) * C_ + (c0 + tx)] = tile[tx][ty + j];
  }
}

// ---------------------------------------------------------------------------
// Kernel 1: chunked top-4 -- VERBATIM proven R8 structure (94.5us version).
// 1 point/thread, 10 VALU ops/key; TOPK_BLOCK=1024 -> <=64 VGPR -> 2
// blocks/CU -> two 2KB uniform s_load streams fit the scalar K$.
// Keys: d^2+1 with 7-bit local index in low mantissa; KEEP=4 absorbs
// same-quantum collisions; merge re-ranks all 8x4 candidates in f64.
// DO NOT fuse other roles into this kernel: its 64-VGPR/2-block contract
// is the whole game (R1/R2 lesson: union-kernel regalloc broke it, 167us+).
// ---------------------------------------------------------------------------
__global__ __launch_bounds__(TOPK_BLOCK) void topk_chunk_kernel(
    const float* __restrict__ xyz,   // [B, N, 3]
    const float* __restrict__ csoa,  // [B][NCHUNK][CHUNK/2][8]
    unsigned* __restrict__ cand)     // [B*N][NCHUNK]: 4 packed 8-bit indices
{
  const int b = blockIdx.z;
  const int chunk = blockIdx.y;
  const int n = blockIdx.x * TOPK_BLOCK + threadIdx.x;
  const size_t p = (size_t)b * N_ + n;

  const float* __restrict__ cb =
      csoa + (((size_t)b * NCHUNK + chunk) * (CHUNK / 2)) * 8;

  const float* xp = xyz + p * 3;
  const float x0 = xp[0], x1 = xp[1], x2 = xp[2];
  const float nx0 = -2.f * x0, nx1 = -2.f * x1, nx2 = -2.f * x2;
  const float x2p1 = fmaf(x0, x0, fmaf(x1, x1, fmaf(x2, x2, 1.0f)));

  float A0 = INFINITY, A1 = INFINITY, A2 = INFINITY, A3 = INFINITY;
  float B0 = INFINITY, B1 = INFINITY, B2 = INFINITY, B3 = INFINITY;

#pragma unroll 8
  for (int i = 0; i < CHUNK / 2; ++i) {
    const float* pb = cb + i * 8;
    float tx = fmaf(nx0, pb[0], x2p1), ty = fmaf(nx0, pb[1], x2p1);
    tx = fmaf(nx1, pb[2], tx); ty = fmaf(nx1, pb[3], ty);
    tx = fmaf(nx2, pb[4], tx); ty = fmaf(nx2, pb[5], ty);
    tx += pb[6]; ty += pb[7];  // key = d^2 + 1 > 0
    // pack 7-bit local index into low mantissa bits
    const float kx = __uint_as_float((__float_as_uint(tx) & 0xFFFFFF80u) | (unsigned)(2 * i));
    const float ky = __uint_as_float((__float_as_uint(ty) & 0xFFFFFF80u) | (unsigned)(2 * i + 1));
    INSERT4(A, kx);
    INSERT4(B, ky);
  }
  // fold chain B into chain A (exact running-inserts)
  INSERT4(A, B0);
  INSERT4(A, B1);
  INSERT4(A, B2);
  INSERT4(A, B3);

  const unsigned i0 = __float_as_uint(A0) & 127u;
  const unsigned i1 = __float_as_uint(A1) & 127u;
  const unsigned i2 = __float_as_uint(A2) & 127u;
  const unsigned i3 = __float_as_uint(A3) & 127u;
  cand[p * NCHUNK + chunk] = i0 | (i1 << 8) | (i2 << 16) | (i3 << 24);
}

// ---------------------------------------------------------------------------
// Kernel 2 (fused merge+gather): 256-thread block owns 256 consecutive
// points (all same batch: 16384 % 256 == 0).
//   Phase A (merge): all 256 threads in parallel, one point each -- f64
//     re-rank of the 8x4 candidates, stable strict-< insertion, weights.
//     Byte-identical math to the proven standalone merge kernel. Results
//     to LDS (saves the 6 MB idx/w global round-trip + one launch).
//   Phase B (gather): 4 waves x 64 points; lane l handles channels
//     [4l,4l+4) as float4. fT rows are 1 KB contiguous -> coalesced; fT
//     per batch is 1 MB -> XCD-L2 resident. Output stores are NON-TEMPORAL
//     (134 MB streaming, never re-read) so they evict-first instead of
//     flushing fT out of the 4 MB XCD L2.
// Standalone kernel => its ~80-VGPR f64 path sets only ITS occupancy
// (~6 blocks/CU), not topk's.
// ---------------------------------------------------------------------------
__global__ __launch_bounds__(256) void mg_kernel(
    const float* __restrict__ xyz,     // [B, N, 3]
    const float4* __restrict__ cpack,  // [B*M]
    const unsigned* __restrict__ cand, // [B*N][NCHUNK]
    const float* __restrict__ fT,      // [B, M, C]
    float* __restrict__ out)           // [B, N, C]
{
  __shared__ int   sI[256 * 3];
  __shared__ float sW[256 * 3];
  const int tid = threadIdx.x;
  const size_t pbase = (size_t)blockIdx.x * 256;
  const int b = (int)(pbase >> 14);  // / N_

  {  // ---- Phase A: merge (verbatim math from proven merge_kernel) ----
    const size_t p = pbase + tid;
    const float* xp = xyz + p * 3;
    const double x0d = (double)xp[0], x1d = (double)xp[1], x2d = (double)xp[2];
    const float4* __restrict__ cb = cpack + (size_t)b * M_;

    const uint4* cw4 = (const uint4*)(cand + p * NCHUNK);
    const uint4 ca = cw4[0], cb2 = cw4[1];
    unsigned words[NCHUNK] = {ca.x, ca.y, ca.z, ca.w, cb2.x, cb2.y, cb2.z, cb2.w};

    double D0 = 1e300, D1 = 1e300, D2 = 1e300;
    int I0 = 0, I1 = 0, I2 = 0;
#pragma unroll
    for (int ch = 0; ch < NCHUNK; ++ch) {
      const unsigned w = words[ch];
#pragma unroll
      for (int j = 0; j < KEEP; ++j) {
        const int m = ch * CHUNK + (int)((w >> (8 * j)) & 255u);
        const float4 c = cb[m];
        const double cx = (double)c.x, cy = (double)c.y, cz = (double)c.z;
        const double dot = x0d * cx + x1d * cy + x2d * cz;
        const double c2d = cx * cx + cy * cy + cz * cz;
        const double kd = c2d - 2.0 * dot;
        if (kd < D2) {
          if (kd < D1) {
            D2 = D1; I2 = I1;
            if (kd < D0) { D1 = D0; I1 = I0; D0 = kd; I0 = m; }
            else         { D1 = kd; I1 = m; }
          } else {
            D2 = kd; I2 = m;
          }
        }
      }
    }

    const double xx = x0d * x0d + x1d * x1d + x2d * x2d;
    const float d0 = sqrtf(fmaxf((float)(xx + D0), 0.0f));
    const float d1 = sqrtf(fmaxf((float)(xx + D1), 0.0f));
    const float d2 = sqrtf(fmaxf((float)(xx + D2), 0.0f));
    float w0 = 1.0f / fmaxf(d0, 1e-8f);
    float w1 = 1.0f / fmaxf(d1, 1e-8f);
    float w2 = 1.0f / fmaxf(d2, 1e-8f);
    const float wsum = w0 + w1 + w2;
    w0 /= wsum; w1 /= wsum; w2 /= wsum;

    sI[tid * 3 + 0] = I0; sI[tid * 3 + 1] = I1; sI[tid * 3 + 2] = I2;
    sW[tid * 3 + 0] = w0; sW[tid * 3 + 1] = w1; sW[tid * 3 + 2] = w2;
  }
  __syncthreads();

  // ---- Phase B: gather (proven wave-per-point pattern; nt store) ----
  const int wid = tid >> 6;
  const int lane = tid & 63;
  const float4* __restrict__ f4 = (const float4*)(fT + (size_t)b * M_ * C_);
  nfloat4* __restrict__ o4 = (nfloat4*)out;
#pragma unroll 2
  for (int j = 0; j < 64; ++j) {   // 4 waves x 64 points = 256
    const int li = wid * 64 + j;
    const size_t p = pbase + li;
    const int i0 = sI[li * 3 + 0], i1 = sI[li * 3 + 1], i2 = sI[li * 3 + 2];
    const float w0 = sW[li * 3 + 0], w1 = sW[li * 3 + 1], w2 = sW[li * 3 + 2];

    float4 a  = f4[(size_t)i0 * (C_ / 4) + lane];
    float4 bb = f4[(size_t)i1 * (C_ / 4) + lane];
    float4 c  = f4[(size_t)i2 * (C_ / 4) + lane];

    nfloat4 rr;
    rr.x = w0 * a.x + w1 * bb.x + w2 * c.x;
    rr.y = w0 * a.y + w1 * bb.y + w2 * c.y;
    rr.z = w0 * a.z + w1 * bb.z + w2 * c.z;
    rr.w = w0 * a.w + w1 * bb.w + w2 * c.w;

    __builtin_nontemporal_store(rr, &o4[p * (C_ / 4) + lane]);
  }
}

extern "C" void kernel_launch(void* const* d_in, const int* in_sizes, int n_in,
                              void* d_out, int out_size, void* d_ws, size_t ws_size,
                              hipStream_t stream) {
  const float* xyz  = (const float*)d_in[0];  // [B, N, 3]
  const float* cxyz = (const float*)d_in[1];  // [B, M, 3]
  const float* cf   = (const float*)d_in[2];  // [B, C, M]
  float* out = (float*)d_out;                 // [B, N, C]

  char* ws = (char*)d_ws;
  float4* cpack = (float4*)ws;                          // B*M float4 (128 KB)
  size_t off = (size_t)B_ * M_ * sizeof(float4);
  float* csoa = (float*)(ws + off);                     // B*M*4 floats (128 KB)
  off += (size_t)B_ * M_ * 4 * sizeof(float);
  off = (off + 255) & ~(size_t)255;
  unsigned* cand = (unsigned*)(ws + off);               // B*N*NCHUNK*4B = 4.2 MB
  off += ((size_t)B_ * N_ * NCHUNK * 4 + 255) & ~(size_t)255;
  float* fT = (float*)(ws + off);                       // B*M*C floats = 8 MB

  const size_t npts = (size_t)B_ * N_;
  prep_kernel<<<dim3(32 + 2048), dim3(32, 8), 0, stream>>>(
      cxyz, cf, csoa, cpack, fT);
  topk_chunk_kernel<<<dim3(N_ / TOPK_BLOCK, NCHUNK, B_), TOPK_BLOCK, 0, stream>>>(
      xyz, csoa, cand);
  mg_kernel<<<(unsigned)(npts / 256), 256, 0, stream>>>(
      xyz, cpack, cand, fT, out);
}

// Round 5
// 86.396 us; speedup vs baseline: 2.1237x; 1.2505x over previous
//
#include <hip/hip_runtime.h>
#include <math.h>

// Problem constants (fixed by setup_inputs)
constexpr int B_ = 8;
constexpr int N_ = 16384;
constexpr int M_ = 1024;
constexpr int C_ = 256;
constexpr int NCHUNK = 8;
constexpr int CHUNK = M_ / NCHUNK;  // 128
constexpr int KEEP = 4;             // per-chunk survivors
constexpr int TOPK_BLOCK = 1024;    // 16 waves/block -> 2 blocks/CU -> 2 K$ streams

// native 4-float vector for __builtin_nontemporal_store (HIP's float4 is a
// class type the builtin rejects; ext_vector_type is accepted).
typedef float nfloat4 __attribute__((ext_vector_type(4)));

// 4-deep sorted-insert network on POSITIVE floats (P0<=P1<=P2<=P3 invariant).
// min + 3x v_med3_f32, all VOP3-legal, no SGPR operands.
#define INSERT4(P, u)                                              \
  {                                                                \
    const float o0 = P##0, o1 = P##1, o2 = P##2;                   \
    P##0 = fminf(o0, (u));                                         \
    P##1 = __builtin_amdgcn_fmed3f(o0, P##1, (u));                 \
    P##2 = __builtin_amdgcn_fmed3f(o1, P##2, (u));                 \
    P##3 = __builtin_amdgcn_fmed3f(o2, P##3, (u));                 \
  }

// ---------------------------------------------------------------------------
// Kernel 0 (fused prep): blocks [0,32) pack centroids; blocks [32, 32+2048)
// transpose centroid_f [B,C,M] -> fT [B,M,C] via 32x32 LDS tiles (+1 pad).
// ---------------------------------------------------------------------------
__global__ __launch_bounds__(256) void prep_kernel(
    const float* __restrict__ cxyz,  // [B, M, 3]
    const float* __restrict__ cf,    // [B, C, M]
    float* __restrict__ csoa,        // [B][NCHUNK][CHUNK/2][8]
    float4* __restrict__ cpack,      // [B*M]
    float* __restrict__ fT)          // [B, M, C]
{
  __shared__ float tile[32][33];
  const int tx = threadIdx.x;  // 0..31
  const int ty = threadIdx.y;  // 0..7
  if (blockIdx.x < 32) {
    // ---- pack role ----
    const int i = blockIdx.x * 256 + (ty * 32 + tx);  // global centroid id
    if (i < B_ * M_) {
      const int b = i >> 10;         // / M_
      const int m = i & (M_ - 1);
      const int chunk = m >> 7;      // / CHUNK
      const int mi = m & (CHUNK - 1);
      const int pair = mi >> 1;
      const int sub = mi & 1;
      const float x = cxyz[3 * i + 0];
      const float y = cxyz[3 * i + 1];
      const float z = cxyz[3 * i + 2];
      const float w = x * x + y * y + z * z;
      float* pb = csoa + ((((size_t)b * NCHUNK + chunk) * (CHUNK / 2)) + pair) * 8 + sub;
      pb[0] = x; pb[2] = y; pb[4] = z; pb[6] = w;
      cpack[i] = make_float4(x, y, z, w);
    }
  } else {
    // ---- transpose role ----
    const int bid = blockIdx.x - 32;       // 0..2047
    const int m0 = (bid & 31) * 32;        // M/32 = 32
    const int c0 = ((bid >> 5) & 7) * 32;  // C/32 = 8
    const int b = bid >> 8;
    const float* fb = cf + (size_t)b * C_ * M_;
    float* ftb = fT + (size_t)b * M_ * C_;
#pragma unroll
    for (int j = 0; j < 32; j += 8)
      tile[ty + j][tx] = fb[(size_t)(c0 + ty + j) * M_ + (m0 + tx)];
    __syncthreads();
#pragma unroll
    for (int j = 0; j < 32; j += 8)
      ftb[(size_t)(m0 + ty + j) * C_ + (c0 + tx)] = tile[tx][ty + j];
  }
}

// ---------------------------------------------------------------------------
// Kernel 1: chunked top-4 -- VERBATIM proven R8 structure (94.5us version).
// 1 point/thread, 10 VALU ops/key; TOPK_BLOCK=1024 -> <=64 VGPR -> 2
// blocks/CU -> two uniform s_load streams fit the scalar K$.
// DO NOT fuse other roles into this kernel (R1/R2 lesson: union-kernel
// regalloc broke its 64-VGPR/8-wave-per-SIMD contract, 167-183us).
// ---------------------------------------------------------------------------
__global__ __launch_bounds__(TOPK_BLOCK) void topk_chunk_kernel(
    const float* __restrict__ xyz,   // [B, N, 3]
    const float* __restrict__ csoa,  // [B][NCHUNK][CHUNK/2][8]
    unsigned* __restrict__ cand)     // [B*N][NCHUNK]: 4 packed 8-bit indices
{
  const int b = blockIdx.z;
  const int chunk = blockIdx.y;
  const int n = blockIdx.x * TOPK_BLOCK + threadIdx.x;
  const size_t p = (size_t)b * N_ + n;

  const float* __restrict__ cb =
      csoa + (((size_t)b * NCHUNK + chunk) * (CHUNK / 2)) * 8;

  const float* xp = xyz + p * 3;
  const float x0 = xp[0], x1 = xp[1], x2 = xp[2];
  const float nx0 = -2.f * x0, nx1 = -2.f * x1, nx2 = -2.f * x2;
  const float x2p1 = fmaf(x0, x0, fmaf(x1, x1, fmaf(x2, x2, 1.0f)));

  float A0 = INFINITY, A1 = INFINITY, A2 = INFINITY, A3 = INFINITY;
  float B0 = INFINITY, B1 = INFINITY, B2 = INFINITY, B3 = INFINITY;

#pragma unroll 8
  for (int i = 0; i < CHUNK / 2; ++i) {
    const float* pb = cb + i * 8;
    float tx = fmaf(nx0, pb[0], x2p1), ty = fmaf(nx0, pb[1], x2p1);
    tx = fmaf(nx1, pb[2], tx); ty = fmaf(nx1, pb[3], ty);
    tx = fmaf(nx2, pb[4], tx); ty = fmaf(nx2, pb[5], ty);
    tx += pb[6]; ty += pb[7];  // key = d^2 + 1 > 0
    // pack 7-bit local index into low mantissa bits
    const float kx = __uint_as_float((__float_as_uint(tx) & 0xFFFFFF80u) | (unsigned)(2 * i));
    const float ky = __uint_as_float((__float_as_uint(ty) & 0xFFFFFF80u) | (unsigned)(2 * i + 1));
    INSERT4(A, kx);
    INSERT4(B, ky);
  }
  // fold chain B into chain A (exact running-inserts)
  INSERT4(A, B0);
  INSERT4(A, B1);
  INSERT4(A, B2);
  INSERT4(A, B3);

  const unsigned i0 = __float_as_uint(A0) & 127u;
  const unsigned i1 = __float_as_uint(A1) & 127u;
  const unsigned i2 = __float_as_uint(A2) & 127u;
  const unsigned i3 = __float_as_uint(A3) & 127u;
  cand[p * NCHUNK + chunk] = i0 | (i1 << 8) | (i2 << 16) | (i3 << 24);
}

// ---------------------------------------------------------------------------
// Kernel 2: merge 8x4 candidates -> exact global top-3 + weights. VERBATIM
// proven structure (f64 re-rank, stable strict-< insertion). Standalone so
// its ~90-VGPR f64 path sets only its own occupancy (R4 lesson: fusing it
// into gather cut gather's block count 64x and cost 13us).
// ---------------------------------------------------------------------------
__global__ __launch_bounds__(256) void merge_kernel(
    const float* __restrict__ xyz,     // [B, N, 3]
    const float4* __restrict__ cpack,  // [B*M]
    const unsigned* __restrict__ cand, // [B*N][NCHUNK]
    int*   __restrict__ out_idx,       // [B*N, 3]
    float* __restrict__ out_w)         // [B*N, 3]
{
  const size_t p = (size_t)blockIdx.x * 256 + threadIdx.x;
  const int b = (int)(p >> 14);  // p / N_

  const float* xp = xyz + p * 3;
  const double x0d = (double)xp[0], x1d = (double)xp[1], x2d = (double)xp[2];
  const float4* __restrict__ cb = cpack + (size_t)b * M_;

  const uint4* cw4 = (const uint4*)(cand + p * NCHUNK);
  const uint4 ca = cw4[0], cb2 = cw4[1];
  unsigned words[NCHUNK] = {ca.x, ca.y, ca.z, ca.w, cb2.x, cb2.y, cb2.z, cb2.w};

  double D0 = 1e300, D1 = 1e300, D2 = 1e300;
  int I0 = 0, I1 = 0, I2 = 0;
#pragma unroll
  for (int ch = 0; ch < NCHUNK; ++ch) {
    const unsigned w = words[ch];
#pragma unroll
    for (int j = 0; j < KEEP; ++j) {
      const int m = ch * CHUNK + (int)((w >> (8 * j)) & 255u);
      const float4 c = cb[m];
      const double cx = (double)c.x, cy = (double)c.y, cz = (double)c.z;
      const double dot = x0d * cx + x1d * cy + x2d * cz;
      const double c2d = cx * cx + cy * cy + cz * cz;
      const double kd = c2d - 2.0 * dot;
      if (kd < D2) {
        if (kd < D1) {
          D2 = D1; I2 = I1;
          if (kd < D0) { D1 = D0; I1 = I0; D0 = kd; I0 = m; }
          else         { D1 = kd; I1 = m; }
        } else {
          D2 = kd; I2 = m;
        }
      }
    }
  }

  const double xx = x0d * x0d + x1d * x1d + x2d * x2d;
  const float d0 = sqrtf(fmaxf((float)(xx + D0), 0.0f));
  const float d1 = sqrtf(fmaxf((float)(xx + D1), 0.0f));
  const float d2 = sqrtf(fmaxf((float)(xx + D2), 0.0f));
  float w0 = 1.0f / fmaxf(d0, 1e-8f);
  float w1 = 1.0f / fmaxf(d1, 1e-8f);
  float w2 = 1.0f / fmaxf(d2, 1e-8f);
  const float wsum = w0 + w1 + w2;
  w0 /= wsum; w1 /= wsum; w2 /= wsum;

  const size_t o = p * 3;
  out_idx[o + 0] = I0; out_idx[o + 1] = I1; out_idx[o + 2] = I2;
  out_w[o + 0] = w0;   out_w[o + 1] = w1;   out_w[o + 2] = w2;
}

// ---------------------------------------------------------------------------
// Kernel 3: weighted feature gather -- proven wave-per-point structure, with
// two L2-locality fixes:
//   (1) batch<->XCD swizzle: remap block -> point-group so batch==blockIdx%8.
//       With MI355X's round-robin block->XCD dispatch, each XCD then serves
//       ONE batch -> its fT working set is 1 MB (fits the 4 MB XCD L2),
//       instead of all 8 batches (8 MB) thrashing every XCD.
//   (2) non-temporal output stores: the 134 MB write stream marks evict-first
//       instead of flushing fT out of L2 between row reuses.
// Mapping is a perf heuristic only (pure index permutation; correctness is
// dispatch-order independent).
// ---------------------------------------------------------------------------
__global__ __launch_bounds__(256) void gather_kernel(
    const float* __restrict__ fT,   // [B, M, C]
    const int*   __restrict__ idx,  // [B*N, 3]
    const float* __restrict__ w,    // [B*N, 3]
    float* __restrict__ out)        // [B, N, C]
{
  const int wid  = threadIdx.x >> 6;
  const int lane = threadIdx.x & 63;
  // batch<->XCD swizzle: 32768 groups of 4 points; 4096 groups per batch.
  const int g = (blockIdx.x & 7) * 4096 + (blockIdx.x >> 3);
  const size_t p = (size_t)g * 4 + wid;  // global point id
  const int b = (int)(p >> 14);          // p / N_  (== blockIdx.x & 7)

  const size_t o = p * 3;
  const int i0 = idx[o + 0], i1 = idx[o + 1], i2 = idx[o + 2];
  const float w0 = w[o + 0], w1 = w[o + 1], w2 = w[o + 2];

  const float4* f4 = (const float4*)(fT + (size_t)b * M_ * C_);
  float4 a = f4[(size_t)i0 * (C_ / 4) + lane];
  float4 bb = f4[(size_t)i1 * (C_ / 4) + lane];
  float4 c = f4[(size_t)i2 * (C_ / 4) + lane];

  nfloat4 r;
  r.x = w0 * a.x + w1 * bb.x + w2 * c.x;
  r.y = w0 * a.y + w1 * bb.y + w2 * c.y;
  r.z = w0 * a.z + w1 * bb.z + w2 * c.z;
  r.w = w0 * a.w + w1 * bb.w + w2 * c.w;

  __builtin_nontemporal_store(r, &((nfloat4*)out)[p * (C_ / 4) + lane]);
}

extern "C" void kernel_launch(void* const* d_in, const int* in_sizes, int n_in,
                              void* d_out, int out_size, void* d_ws, size_t ws_size,
                              hipStream_t stream) {
  const float* xyz  = (const float*)d_in[0];  // [B, N, 3]
  const float* cxyz = (const float*)d_in[1];  // [B, M, 3]
  const float* cf   = (const float*)d_in[2];  // [B, C, M]
  float* out = (float*)d_out;                 // [B, N, C]

  char* ws = (char*)d_ws;
  const size_t npts = (size_t)B_ * N_;

  int*    idxbuf = (int*)ws;                              // npts*3 ints
  float*  wbuf   = (float*)(ws + npts * 3 * sizeof(int)); // npts*3 floats
  size_t  off    = npts * 3 * 8;
  float4* cpack  = (float4*)(ws + off);                   // B*M float4 (128 KB)
  off += (size_t)B_ * M_ * sizeof(float4);
  float*  csoa   = (float*)(ws + off);                    // B*M*4 floats (128 KB)
  off += (size_t)B_ * M_ * 4 * sizeof(float);
  off = (off + 15) & ~(size_t)15;
  char*   region = ws + off;
  unsigned* cand = (unsigned*)region;  // npts*NCHUNK*4B = 4.2 MB
  size_t cand_bytes = (npts * (size_t)NCHUNK * 4 + 255) & ~(size_t)255;
  float* fT = (float*)(region + cand_bytes);  // B*M*C floats = 8 MB

  prep_kernel<<<dim3(32 + 2048), dim3(32, 8), 0, stream>>>(
      cxyz, cf, csoa, cpack, fT);
  topk_chunk_kernel<<<dim3(N_ / TOPK_BLOCK, NCHUNK, B_), TOPK_BLOCK, 0, stream>>>(
      xyz, csoa, cand);
  merge_kernel<<<(unsigned)(npts / 256), 256, 0, stream>>>(
      xyz, cpack, cand, idxbuf, wbuf);
  gather_kernel<<<(unsigned)(npts / 4), 256, 0, stream>>>(fT, idxbuf, wbuf, out);
}